// Round 5
// baseline (242.169 us; speedup 1.0000x reference)
//
#include <hip/hip_runtime.h>

// yoloLoss on MI355X — R5: persistent waves + regular-load VGPR pipeline.
// R1/R3/R4 (all global_load_lds-staged) stuck at 70-85us: per-tile staging
// cost ~latency*count, consistent with per-wave serialized LDS-DMA (or deep
// downclock). R5: 2560 persistent single-wave blocks (10/CU), each tile's
// 15 float4 staged via ordinary pipelined global_load_dwordx4 -> VGPRs ->
// ds_write_b128 -> ds_read -> compute, prefetching the next tile during
// compute. No barriers, no LDS-DMA. HBM floor ~31 us.

#define FEAT 30
#define CELLS 802816                    // 4096*14*14
#define TILE_CELLS 64
#define TILE_FLOATS (TILE_CELLS * FEAT) // 1920 floats = 7680 B per array
#define NTILES (CELLS / TILE_CELLS)     // 12544
#define GRID 2560                       // 10 blocks/CU * 256 CU, persistent
#define RED_TPB 256

__device__ __forceinline__ float iou_f(float x1, float y1, float w1, float h1,
                                       float x2, float y2, float w2, float h2) {
    float b1x1 = x1 - 0.5f * w1, b1x2 = x1 + 0.5f * w1;
    float b1y1 = y1 - 0.5f * h1, b1y2 = y1 + 0.5f * h1;
    float b2x1 = x2 - 0.5f * w2, b2x2 = x2 + 0.5f * w2;
    float b2y1 = y2 - 0.5f * h2, b2y2 = y2 + 0.5f * h2;
    float iw = fmaxf(fminf(b1x2, b2x2) - fmaxf(b1x1, b2x1), 0.0f);
    float ih = fmaxf(fminf(b1y2, b2y2) - fmaxf(b1y1, b2y1), 0.0f);
    float inter = iw * ih;
    float a1 = (b1x2 - b1x1) * (b1y2 - b1y1);
    float a2 = (b2x2 - b2x1) * (b2y2 - b2y1);
    return inter / (a1 + a2 - inter + 1e-6f);
}

// Verified absmax==0 in R1-R4. p/t: 30 register-resident floats per cell.
__device__ __forceinline__ float cell_loss(const float* p, const float* t) {
    const bool obj0 = t[4] > 0.0f;
    const bool obj1 = t[9] > 0.0f;
    const float mf = obj0 ? 1.0f : 0.0f;

    float d0 = p[4] - t[4];
    float d1 = p[9] - t[9];
    float noobj = (obj0 ? 0.0f : d0 * d0) + (obj1 ? 0.0f : d1 * d1);

    float iou0 = iou_f(p[0], p[1], p[2], p[3], t[0], t[1], t[2], t[3]);
    float iou1 = iou_f(p[5], p[6], p[7], p[8], t[5], t[6], t[7], t[8]);
    const bool sel1 = iou1 > iou0;   // argmax tie -> box 0

    float pbx = sel1 ? p[5] : p[0];
    float pby = sel1 ? p[6] : p[1];
    float pbw = sel1 ? p[7] : p[2];
    float pbh = sel1 ? p[8] : p[3];
    float pbc = sel1 ? p[9] : p[4];
    float tbx = sel1 ? t[5] : t[0];
    float tby = sel1 ? t[6] : t[1];
    float tbw = sel1 ? t[7] : t[2];
    float tbh = sel1 ? t[8] : t[3];
    float tbc = sel1 ? t[9] : t[4];

    float dx = pbx - tbx, dy = pby - tby;
    float xy = dx * dx + dy * dy;

    float pw = sqrtf(fabsf(pbw) + 1e-6f);
    float ph = sqrtf(fabsf(pbh) + 1e-6f);
    float tw = sqrtf(obj0 ? tbw : 1.0f);   // t_wh_safe
    float th = sqrtf(obj0 ? tbh : 1.0f);
    float dw = pw - tw, dh = ph - th;
    float wh = dw * dw + dh * dh;

    float dc = pbc - tbc;
    float obj_l = dc * dc;

    float nonbest = (p[4] + p[9]) - pbc;   // LAMBDA_NOOBJ applied twice (ref)
    noobj += 0.5f * mf * nonbest * nonbest;

    float cls = 0.0f;
#pragma unroll
    for (int k = 10; k < FEAT; ++k) {
        float d = p[k] - t[k];
        cls += d * d;
    }

    return 5.0f * mf * (xy + wh) + mf * obj_l + 0.5f * noobj + mf * cls;
}

// Issue 15 pipelined global_load_dwordx4 for one tile into r[].
// Concatenated float4 index g = j*64+lane over [pred 480 | tgt 480].
// j<=6: pred (static); j==7: per-lane split; j>=8: tgt (static).
__device__ __forceinline__ void prefetch(const float* __restrict__ pred,
                                         const float* __restrict__ tgt,
                                         long long tile, int lane,
                                         float4 r[15]) {
    const float* pb = pred + tile * TILE_FLOATS;
    const float* tb = tgt + tile * TILE_FLOATS;
#pragma unroll
    for (int j = 0; j < 15; ++j) {
        int g = j * 64 + lane;
        const float* src = (g < 480) ? (pb + 4 * g) : (tb + 4 * (g - 480));
        r[j] = *(const float4*)src;
    }
}

__global__ __launch_bounds__(64) void yolo_kernel(
        const float* __restrict__ pred, const float* __restrict__ tgt,
        float* __restrict__ partials) {
    // 15,360 B LDS -> 10 single-wave blocks/CU. [0,1920) pred, [1920,3840) tgt
    __shared__ float lds[2 * TILE_FLOATS];

    const int lane = threadIdx.x;
    float acc = 0.0f;

    long long t = blockIdx.x;
    float4 r[15];
    prefetch(pred, tgt, t, lane, r);

#pragma unroll 1
    for (; t < NTILES; ) {
        // Drain this tile's loads into LDS (same-wave, in-order DS; no barrier).
        float4* L = (float4*)lds;
#pragma unroll
        for (int j = 0; j < 15; ++j) L[j * 64 + lane] = r[j];

        // Prefetch next tile while we compute this one (clamped if past end).
        long long nt = t + GRID;
        prefetch(pred, tgt, (nt < NTILES) ? nt : t, lane, r);

        // LDS -> registers (float2; cell stride 120 B, 8B-aligned)
        const float2* pc = (const float2*)(lds + lane * FEAT);
        const float2* tc = (const float2*)(lds + TILE_FLOATS + lane * FEAT);
        float pf[FEAT], tf[FEAT];
#pragma unroll
        for (int k = 0; k < FEAT / 2; ++k) {
            float2 a = pc[k]; pf[2 * k] = a.x; pf[2 * k + 1] = a.y;
            float2 b = tc[k]; tf[2 * k] = b.x; tf[2 * k + 1] = b.y;
        }
        acc += cell_loss(pf, tf);
        t = nt;
    }

    float v = acc;
#pragma unroll
    for (int off = 32; off > 0; off >>= 1) v += __shfl_down(v, off, 64);
    if (lane == 0) partials[blockIdx.x] = v;
}

__global__ __launch_bounds__(RED_TPB) void yolo_reduce_kernel(
        const float* __restrict__ partials, float* __restrict__ out) {
    __shared__ float wave_sum[RED_TPB / 64];
    const int tid = threadIdx.x;
    float v = 0.0f;
#pragma unroll 1
    for (int i = tid; i < GRID; i += RED_TPB) v += partials[i];
#pragma unroll
    for (int off = 32; off > 0; off >>= 1) v += __shfl_down(v, off, 64);
    if ((tid & 63) == 0) wave_sum[tid >> 6] = v;
    __syncthreads();
    if (tid == 0)
        out[0] = (wave_sum[0] + wave_sum[1] + wave_sum[2] + wave_sum[3]) *
                 (1.0f / 4096.0f);
}

extern "C" void kernel_launch(void* const* d_in, const int* in_sizes, int n_in,
                              void* d_out, int out_size, void* d_ws, size_t ws_size,
                              hipStream_t stream) {
    const float* pred = (const float*)d_in[0];
    const float* tgt  = (const float*)d_in[1];
    float* out = (float*)d_out;
    float* partials = (float*)d_ws;   // 2560 floats = 10 KB << ws_size

    yolo_kernel<<<GRID, 64, 0, stream>>>(pred, tgt, partials);
    yolo_reduce_kernel<<<1, RED_TPB, 0, stream>>>(partials, out);
}